// Round 7
// baseline (2332.397 us; speedup 1.0000x reference)
//
#include <hip/hip_runtime.h>
#include <math.h>

#define B_   32
#define L_   512
#define D_   512
#define H_   8
#define DK_  64
#define NB_  2
#define DFF_ 256
#define NPID_ 10000
#define FC1_ 512
#define FC2_ 256

// ---------------------------------------------------------------------------
// Embedding + cosine positional encoding (unchanged)
// ---------------------------------------------------------------------------
__global__ __launch_bounds__(256) void embed_kernel(
    const int* __restrict__ prob, const int* __restrict__ corr,
    const float* __restrict__ q_embed, const float* __restrict__ qa_embed,
    const float* __restrict__ q_diff, const float* __restrict__ dparam,
    float* __restrict__ qe, float* __restrict__ x, float* __restrict__ y)
{
    int bl = blockIdx.x;            // b*L + l
    int l  = bl & (L_ - 1);
    int q  = prob[bl] + 1;
    int qa = q + corr[bl] * NPID_;
    const float* qe_r = q_embed + (size_t)q  * D_;
    const float* qd_r = q_diff  + (size_t)q  * D_;
    const float* dp_r = dparam  + (size_t)q  * D_;
    const float* qa_r = qa_embed + (size_t)qa * D_;
    size_t ooff = (size_t)bl * D_;
    const float nl = -logf(10000.0f) / (float)D_;
    for (int d = threadIdx.x; d < D_; d += 256) {
        int   i2   = d & ~1;
        float freq = expf((float)i2 * nl);
        float arg  = (float)l * freq;
        float pe   = (d & 1) ? cosf(arg) : sinf(arg);
        float qev  = qe_r[d] + dp_r[d] * qd_r[d];
        qe[ooff + d] = qev;
        x [ooff + d] = qev + pe;
        y [ooff + d] = qa_r[d] + pe;
    }
}

// ---------------------------------------------------------------------------
// fp32 GEMM (unchanged this round)
// ---------------------------------------------------------------------------
template<bool HB, bool RELU, bool ACC, bool RES>
__global__ __launch_bounds__(256) void gemm_kernel(
    const float* __restrict__ A, const float* __restrict__ W,
    const float* __restrict__ bias, const float* __restrict__ resid,
    float* __restrict__ C, int M, int N, int K)
{
    __shared__ float As[16][132];   // [k][m], padded
    __shared__ float Bs[16][132];   // [k][n], padded

    int tid = threadIdx.x;
    int tx = tid & 15, ty = tid >> 4;
    int rowBase = blockIdx.y * 128;
    int colBase = blockIdx.x * 128;

    float acc[8][8];
#pragma unroll
    for (int i = 0; i < 8; ++i)
#pragma unroll
        for (int j = 0; j < 8; ++j) acc[i][j] = 0.f;

    int am = tid >> 2;                 // 0..63
    int ak = (tid & 3) << 2;           // 0,4,8,12
    int bk = tid >> 4;                 // 0..15
    int bn = (tid & 15) << 2;          // 0..60

    for (int k0 = 0; k0 < K; k0 += 16) {
        __syncthreads();
        float4 a0 = *(const float4*)&A[(size_t)(rowBase + am)      * K + k0 + ak];
        float4 a1 = *(const float4*)&A[(size_t)(rowBase + am + 64) * K + k0 + ak];
        float4 b0 = *(const float4*)&W[(size_t)(k0 + bk) * N + colBase + bn];
        float4 b1 = *(const float4*)&W[(size_t)(k0 + bk) * N + colBase + bn + 64];
        As[ak+0][am] = a0.x; As[ak+1][am] = a0.y; As[ak+2][am] = a0.z; As[ak+3][am] = a0.w;
        As[ak+0][am+64] = a1.x; As[ak+1][am+64] = a1.y; As[ak+2][am+64] = a1.z; As[ak+3][am+64] = a1.w;
        *(float4*)&Bs[bk][bn]      = b0;
        *(float4*)&Bs[bk][bn + 64] = b1;
        __syncthreads();

#pragma unroll
        for (int k = 0; k < 16; ++k) {
            float af[8], bf[8];
            *(float4*)&af[0] = *(const float4*)&As[k][ty*4];
            *(float4*)&af[4] = *(const float4*)&As[k][ty*4 + 64];
            *(float4*)&bf[0] = *(const float4*)&Bs[k][tx*4];
            *(float4*)&bf[4] = *(const float4*)&Bs[k][tx*4 + 64];
#pragma unroll
            for (int ri = 0; ri < 8; ++ri)
#pragma unroll
                for (int ci = 0; ci < 8; ++ci)
                    acc[ri][ci] += af[ri] * bf[ci];
        }
    }

#pragma unroll
    for (int rh = 0; rh < 2; ++rh) {
#pragma unroll
        for (int r = 0; r < 4; ++r) {
            int row = rowBase + rh*64 + ty*4 + r;
            size_t roff = (size_t)row * N;
#pragma unroll
            for (int ch = 0; ch < 2; ++ch) {
                int col = colBase + ch*64 + tx*4;
                float v0 = acc[rh*4+r][ch*4+0];
                float v1 = acc[rh*4+r][ch*4+1];
                float v2 = acc[rh*4+r][ch*4+2];
                float v3 = acc[rh*4+r][ch*4+3];
                if constexpr (ACC) {
                    float4 c = *(const float4*)&C[roff + col];
                    v0 += c.x; v1 += c.y; v2 += c.z; v3 += c.w;
                }
                if constexpr (HB) {
                    float4 bb = *(const float4*)&bias[col];
                    v0 += bb.x; v1 += bb.y; v2 += bb.z; v3 += bb.w;
                }
                if constexpr (RES) {
                    float4 rr = *(const float4*)&resid[roff + col];
                    v0 += rr.x; v1 += rr.y; v2 += rr.z; v3 += rr.w;
                }
                if constexpr (RELU) {
                    v0 = fmaxf(v0, 0.f); v1 = fmaxf(v1, 0.f);
                    v2 = fmaxf(v2, 0.f); v3 = fmaxf(v3, 0.f);
                }
                float4 ov; ov.x = v0; ov.y = v1; ov.z = v2; ov.w = v3;
                *(float4*)&C[roff + col] = ov;
            }
        }
    }
}

// ---------------------------------------------------------------------------
// LayerNorm over D=512, one wave per row (unchanged)
// ---------------------------------------------------------------------------
__global__ __launch_bounds__(64) void ln_kernel(
    const float* __restrict__ in, const float* __restrict__ sc,
    const float* __restrict__ bi, float* __restrict__ out)
{
    int row = blockIdx.x, lane = threadIdx.x;
    const float* r = in + (size_t)row * D_;
    float4 v0 = *(const float4*)&r[lane*8];
    float4 v1 = *(const float4*)&r[lane*8 + 4];
    float sum = v0.x+v0.y+v0.z+v0.w + v1.x+v1.y+v1.z+v1.w;
    float ss  = v0.x*v0.x+v0.y*v0.y+v0.z*v0.z+v0.w*v0.w
              + v1.x*v1.x+v1.y*v1.y+v1.z*v1.z+v1.w*v1.w;
#pragma unroll
    for (int o = 1; o < 64; o <<= 1) {
        sum += __shfl_xor(sum, o);
        ss  += __shfl_xor(ss, o);
    }
    float mean = sum * (1.f / D_);
    float var  = ss  * (1.f / D_) - mean * mean;
    float rstd = rsqrtf(var + 1e-5f);
    float4 s0 = *(const float4*)&sc[lane*8];
    float4 s1 = *(const float4*)&sc[lane*8 + 4];
    float4 b0 = *(const float4*)&bi[lane*8];
    float4 b1 = *(const float4*)&bi[lane*8 + 4];
    float* w = out + (size_t)row * D_;
    float4 o0, o1;
    o0.x = (v0.x-mean)*rstd*s0.x + b0.x; o0.y = (v0.y-mean)*rstd*s0.y + b0.y;
    o0.z = (v0.z-mean)*rstd*s0.z + b0.z; o0.w = (v0.w-mean)*rstd*s0.w + b0.w;
    o1.x = (v1.x-mean)*rstd*s1.x + b1.x; o1.y = (v1.y-mean)*rstd*s1.y + b1.y;
    o1.z = (v1.z-mean)*rstd*s1.z + b1.z; o1.w = (v1.w-mean)*rstd*s1.w + b1.w;
    *(float4*)&w[lane*8]     = o0;
    *(float4*)&w[lane*8 + 4] = o1;
}

// ---------------------------------------------------------------------------
// Fused causal attention v2, q==k. Block = (b, h, q-half): 512 blocks.
// 512 threads; thread = (query row, d-half): row r = qt*256 + (t>>1),
// half = t&1 owns 32 of 64 dims -> q[32]+acc[32] stay in VGPRs (<=128).
// K/V staged in 64-row double-buffered LDS tiles (64 KB -> 2 blocks/CU,
// 16 waves/CU). Half-dots combined via __shfl_xor(.,1) (partner lane has
// identical trip counts). Strict-causal (j<r), row 0 zeroed (zero_pad).
// ---------------------------------------------------------------------------
#define QT_ 256
#define JT_ 64
__global__ __launch_bounds__(512, 4) void attn_kernel(
    const float* __restrict__ qk, const float* __restrict__ vv,
    float* __restrict__ o)
{
    __shared__ float Ksh[2][JT_][DK_];   // 32 KB
    __shared__ float Vsh[2][JT_][DK_];   // 32 KB

    int blk = blockIdx.x;
    int qt  = blk & 1;                   // which 256-row query half
    int bh  = blk >> 1;
    int b = bh >> 3, h = bh & 7;
    const float* kbase = qk + (size_t)b * L_ * D_ + h * DK_;
    const float* vbase = vv + (size_t)b * L_ * D_ + h * DK_;
    int t   = threadIdx.x;
    int r   = qt * QT_ + (t >> 1);       // query row
    int dof = (t & 1) * 32;              // d-half offset

    // my q half (8 float4), pre-scaled by 1/sqrt(dk)
    float q[32];
    {
        const float* qrow = kbase + (size_t)r * D_ + dof;
#pragma unroll
        for (int c = 0; c < 8; ++c) {
            float4 v = *(const float4*)&qrow[c*4];
            q[c*4+0]=v.x*0.125f; q[c*4+1]=v.y*0.125f;
            q[c*4+2]=v.z*0.125f; q[c*4+3]=v.w*0.125f;
        }
    }
    float acc[32];
#pragma unroll
    for (int d = 0; d < 32; ++d) acc[d] = 0.f;
    float m = -3.0e38f, s = 0.f;

    // staging geometry: 1024 float4 per 64x64 tile, 2 per thread
    int f0 = t, f1 = 512 + t;
    int j0s = f0 >> 4, d0s = (f0 & 15) << 2;
    int j1s = f1 >> 4, d1s = (f1 & 15) << 2;

    const int ntiles = (qt + 1) * 4;     // 4 or 8 j-tiles

    // prologue: stage tile 0 into buf 0
    {
        *(float4*)&Ksh[0][j0s][d0s] = *(const float4*)&kbase[(size_t)j0s * D_ + d0s];
        *(float4*)&Ksh[0][j1s][d1s] = *(const float4*)&kbase[(size_t)j1s * D_ + d1s];
        *(float4*)&Vsh[0][j0s][d0s] = *(const float4*)&vbase[(size_t)j0s * D_ + d0s];
        *(float4*)&Vsh[0][j1s][d1s] = *(const float4*)&vbase[(size_t)j1s * D_ + d1s];
    }
    __syncthreads();

    for (int tile = 0; tile < ntiles; ++tile) {
        int cur = tile & 1;
        // T14: issue next tile's global loads BEFORE compute; write after
        float4 nk0, nk1, nv0, nv1;
        bool have_next = (tile + 1 < ntiles);
        if (have_next) {
            size_t jt1 = (size_t)(tile + 1) * JT_;
            nk0 = *(const float4*)&kbase[(jt1 + j0s) * D_ + d0s];
            nk1 = *(const float4*)&kbase[(jt1 + j1s) * D_ + d1s];
            nv0 = *(const float4*)&vbase[(jt1 + j0s) * D_ + d0s];
            nv1 = *(const float4*)&vbase[(jt1 + j1s) * D_ + d1s];
        }

        int jt = tile * JT_;
        int jmax = min(r, jt + JT_);     // strictly lower: j < r
        for (int jb = jt; jb < jmax; jb += 16) {
            float sc[16];
            float tmax = -3.0e38f;
#pragma unroll
            for (int jj = 0; jj < 16; ++jj) {
                const float* kr = &Ksh[cur][jb - jt + jj][dof];
                float d0 = 0.f, d1 = 0.f, d2 = 0.f, d3 = 0.f;
#pragma unroll
                for (int c = 0; c < 8; ++c) {
                    float4 kv = *(const float4*)&kr[c*4];
                    d0 += q[c*4+0]*kv.x; d1 += q[c*4+1]*kv.y;
                    d2 += q[c*4+2]*kv.z; d3 += q[c*4+3]*kv.w;
                }
                float hd = (d0 + d1) + (d2 + d3);
                float sv = hd + __shfl_xor(hd, 1);   // combine halves
                sv = (jb + jj < jmax) ? sv : -3.0e38f;
                sc[jj] = sv;
                tmax = fmaxf(tmax, sv);
            }
            float mnew = fmaxf(m, tmax);             // tmax finite (jj=0 valid)
            float cor  = __expf(m - mnew);
            s *= cor;
#pragma unroll
            for (int d = 0; d < 32; ++d) acc[d] *= cor;
#pragma unroll
            for (int jj = 0; jj < 16; ++jj) {
                float p = __expf(sc[jj] - mnew);     // masked -> 0
                s += p;
                const float* vr = &Vsh[cur][jb - jt + jj][dof];
#pragma unroll
                for (int c = 0; c < 8; ++c) {
                    float4 vw = *(const float4*)&vr[c*4];
                    acc[c*4+0] += p * vw.x; acc[c*4+1] += p * vw.y;
                    acc[c*4+2] += p * vw.z; acc[c*4+3] += p * vw.w;
                }
            }
            m = mnew;
        }

        if (have_next) {                 // write-late: lands before barrier
            int nxt = cur ^ 1;
            *(float4*)&Ksh[nxt][j0s][d0s] = nk0;
            *(float4*)&Ksh[nxt][j1s][d1s] = nk1;
            *(float4*)&Vsh[nxt][j0s][d0s] = nv0;
            *(float4*)&Vsh[nxt][j1s][d1s] = nv1;
        }
        __syncthreads();
    }

    float rs = (r > 0 && s > 0.f) ? (1.f / s) : 0.f;   // zero_pad row 0
    float* orow = o + ((size_t)b * L_ + r) * D_ + h * DK_ + dof;
#pragma unroll
    for (int c = 0; c < 8; ++c) {
        float4 w;
        w.x = acc[c*4+0]*rs; w.y = acc[c*4+1]*rs;
        w.z = acc[c*4+2]*rs; w.w = acc[c*4+3]*rs;
        *(float4*)&orow[c*4] = w;
    }
}

// ---------------------------------------------------------------------------
// Final logits: dot(h2[row], w3) + b3 -> sigmoid -> out (drop l==0)
// ---------------------------------------------------------------------------
__global__ __launch_bounds__(64) void head_out_kernel(
    const float* __restrict__ h2, const float* __restrict__ w3,
    const float* __restrict__ b3, float* __restrict__ out)
{
    int row = blockIdx.x, lane = threadIdx.x;
    float4 hv = *(const float4*)&h2[(size_t)row * FC2_ + lane*4];
    float4 wv = *(const float4*)&w3[lane*4];
    float d = hv.x*wv.x + hv.y*wv.y + hv.z*wv.z + hv.w*wv.w;
#pragma unroll
    for (int o = 1; o < 64; o <<= 1) d += __shfl_xor(d, o);
    if (lane == 0) {
        int l = row & (L_ - 1), b = row >> 9;
        if (l > 0) {
            float logit = d + b3[0];
            out[(size_t)b * (L_ - 1) + l - 1] = 1.f / (1.f + expf(-logit));
        }
    }
}

// ---------------------------------------------------------------------------
extern "C" void kernel_launch(void* const* d_in, const int* in_sizes, int n_in,
                              void* d_out, int out_size, void* d_ws, size_t ws_size,
                              hipStream_t stream)
{
    const int*   prob    = (const int*)d_in[0];
    const int*   corr    = (const int*)d_in[1];
    const float* q_embed = (const float*)d_in[2];
    const float* qa_emb  = (const float*)d_in[3];
    const float* q_diff  = (const float*)d_in[4];
    const float* dparam  = (const float*)d_in[5];
    const float* kw   = (const float*)d_in[6];
    const float* kb   = (const float*)d_in[7];
    const float* vw   = (const float*)d_in[8];
    const float* vb   = (const float*)d_in[9];
    const float* ow   = (const float*)d_in[10];
    const float* ob   = (const float*)d_in[11];
    const float* ln1s = (const float*)d_in[12];
    const float* ln1b = (const float*)d_in[13];
    const float* w1   = (const float*)d_in[14];
    const float* b1   = (const float*)d_in[15];
    const float* w2   = (const float*)d_in[16];
    const float* b2   = (const float*)d_in[17];
    const float* ln2s = (const float*)d_in[18];
    const float* ln2b = (const float*)d_in[19];
    const float* ow1  = (const float*)d_in[20];
    const float* ob1  = (const float*)d_in[21];
    const float* ow2  = (const float*)d_in[22];
    const float* ob2  = (const float*)d_in[23];
    const float* ow3  = (const float*)d_in[24];
    const float* ob3  = (const float*)d_in[25];
    float* out = (float*)d_out;

    const size_t SZ = (size_t)B_ * L_ * D_;     // 8.39M floats
    float* qe = (float*)d_ws;
    float* x  = qe + SZ;
    float* y  = x  + SZ;
    float* t0 = y  + SZ;
    float* t1 = t0 + SZ;
    float* t2 = t1 + SZ;
    float* t3 = t2 + SZ;                         // M x 256 (uses SZ/2)

    const int M = B_ * L_;                       // 16384
    dim3 g512(512 / 128, M / 128);
    dim3 g256(256 / 128, M / 128);

    embed_kernel<<<M, 256, 0, stream>>>(prob, corr, q_embed, qa_emb, q_diff, dparam,
                                        qe, x, y);

    for (int i = 0; i < NB_; ++i) {
        // qk = x@kw + kb   (q == k, single projection)
        gemm_kernel<true,false,false,false><<<g512, 256, 0, stream>>>(
            x, kw + (size_t)i*D_*D_, kb + i*D_, nullptr, t0, M, D_, D_);
        // v = y@vw + vb
        gemm_kernel<true,false,false,false><<<g512, 256, 0, stream>>>(
            y, vw + (size_t)i*D_*D_, vb + i*D_, nullptr, t1, M, D_, D_);
        // o = attn(qk, v)
        attn_kernel<<<B_*H_*2, 512, 0, stream>>>(t0, t1, t2);
        // t0 = x + o@ow + ob
        gemm_kernel<true,false,false,true><<<g512, 256, 0, stream>>>(
            t2, ow + (size_t)i*D_*D_, ob + i*D_, x, t0, M, D_, D_);
        // x = LN1(t0)
        ln_kernel<<<M, 64, 0, stream>>>(t0, ln1s + i*D_, ln1b + i*D_, x);
        // t3 = relu(x@w1 + b1)
        gemm_kernel<true,true,false,false><<<g256, 256, 0, stream>>>(
            x, w1 + (size_t)i*D_*DFF_, b1 + i*DFF_, nullptr, t3, M, DFF_, D_);
        // t2 = x + t3@w2 + b2
        gemm_kernel<true,false,false,true><<<g512, 256, 0, stream>>>(
            t3, w2 + (size_t)i*DFF_*D_, b2 + i*D_, x, t2, M, D_, DFF_);
        // x = LN2(t2)
        ln_kernel<<<M, 64, 0, stream>>>(t2, ln2s + i*D_, ln2b + i*D_, x);
    }

    // head: h1 = relu([x,qe]@ow1 + ob1) done as two GEMMs (split-K of concat)
    gemm_kernel<true,false,false,false><<<g512, 256, 0, stream>>>(
        x, ow1, ob1, nullptr, t0, M, FC1_, D_);
    gemm_kernel<false,true,true,false><<<g512, 256, 0, stream>>>(
        qe, ow1 + (size_t)D_*FC1_, nullptr, nullptr, t0, M, FC1_, D_);
    // h2 = relu(h1@ow2 + ob2)
    gemm_kernel<true,true,false,false><<<g256, 256, 0, stream>>>(
        t0, ow2, ob2, nullptr, t3, M, FC2_, FC1_);
    // logits + sigmoid + drop first position
    head_out_kernel<<<M, 64, 0, stream>>>(t3, ow3, ob3, out);
}

// Round 9
// 2158.154 us; speedup vs baseline: 1.0807x; 1.0807x over previous
//
#include <hip/hip_runtime.h>
#include <math.h>

#define B_   32
#define L_   512
#define D_   512
#define H_   8
#define DK_  64
#define NB_  2
#define DFF_ 256
#define NPID_ 10000
#define FC1_ 512
#define FC2_ 256

// ---------------------------------------------------------------------------
// Embedding + cosine positional encoding (unchanged)
// ---------------------------------------------------------------------------
__global__ __launch_bounds__(256) void embed_kernel(
    const int* __restrict__ prob, const int* __restrict__ corr,
    const float* __restrict__ q_embed, const float* __restrict__ qa_embed,
    const float* __restrict__ q_diff, const float* __restrict__ dparam,
    float* __restrict__ qe, float* __restrict__ x, float* __restrict__ y)
{
    int bl = blockIdx.x;            // b*L + l
    int l  = bl & (L_ - 1);
    int q  = prob[bl] + 1;
    int qa = q + corr[bl] * NPID_;
    const float* qe_r = q_embed + (size_t)q  * D_;
    const float* qd_r = q_diff  + (size_t)q  * D_;
    const float* dp_r = dparam  + (size_t)q  * D_;
    const float* qa_r = qa_embed + (size_t)qa * D_;
    size_t ooff = (size_t)bl * D_;
    const float nl = -logf(10000.0f) / (float)D_;
    for (int d = threadIdx.x; d < D_; d += 256) {
        int   i2   = d & ~1;
        float freq = expf((float)i2 * nl);
        float arg  = (float)l * freq;
        float pe   = (d & 1) ? cosf(arg) : sinf(arg);
        float qev  = qe_r[d] + dp_r[d] * qd_r[d];
        qe[ooff + d] = qev;
        x [ooff + d] = qev + pe;
        y [ooff + d] = qa_r[d] + pe;
    }
}

// ---------------------------------------------------------------------------
// fp32 GEMM (unchanged this round)
// ---------------------------------------------------------------------------
template<bool HB, bool RELU, bool ACC, bool RES>
__global__ __launch_bounds__(256) void gemm_kernel(
    const float* __restrict__ A, const float* __restrict__ W,
    const float* __restrict__ bias, const float* __restrict__ resid,
    float* __restrict__ C, int M, int N, int K)
{
    __shared__ float As[16][132];   // [k][m], padded
    __shared__ float Bs[16][132];   // [k][n], padded

    int tid = threadIdx.x;
    int tx = tid & 15, ty = tid >> 4;
    int rowBase = blockIdx.y * 128;
    int colBase = blockIdx.x * 128;

    float acc[8][8];
#pragma unroll
    for (int i = 0; i < 8; ++i)
#pragma unroll
        for (int j = 0; j < 8; ++j) acc[i][j] = 0.f;

    int am = tid >> 2;                 // 0..63
    int ak = (tid & 3) << 2;           // 0,4,8,12
    int bk = tid >> 4;                 // 0..15
    int bn = (tid & 15) << 2;          // 0..60

    for (int k0 = 0; k0 < K; k0 += 16) {
        __syncthreads();
        float4 a0 = *(const float4*)&A[(size_t)(rowBase + am)      * K + k0 + ak];
        float4 a1 = *(const float4*)&A[(size_t)(rowBase + am + 64) * K + k0 + ak];
        float4 b0 = *(const float4*)&W[(size_t)(k0 + bk) * N + colBase + bn];
        float4 b1 = *(const float4*)&W[(size_t)(k0 + bk) * N + colBase + bn + 64];
        As[ak+0][am] = a0.x; As[ak+1][am] = a0.y; As[ak+2][am] = a0.z; As[ak+3][am] = a0.w;
        As[ak+0][am+64] = a1.x; As[ak+1][am+64] = a1.y; As[ak+2][am+64] = a1.z; As[ak+3][am+64] = a1.w;
        *(float4*)&Bs[bk][bn]      = b0;
        *(float4*)&Bs[bk][bn + 64] = b1;
        __syncthreads();

#pragma unroll
        for (int k = 0; k < 16; ++k) {
            float af[8], bf[8];
            *(float4*)&af[0] = *(const float4*)&As[k][ty*4];
            *(float4*)&af[4] = *(const float4*)&As[k][ty*4 + 64];
            *(float4*)&bf[0] = *(const float4*)&Bs[k][tx*4];
            *(float4*)&bf[4] = *(const float4*)&Bs[k][tx*4 + 64];
#pragma unroll
            for (int ri = 0; ri < 8; ++ri)
#pragma unroll
                for (int ci = 0; ci < 8; ++ci)
                    acc[ri][ci] += af[ri] * bf[ci];
        }
    }

#pragma unroll
    for (int rh = 0; rh < 2; ++rh) {
#pragma unroll
        for (int r = 0; r < 4; ++r) {
            int row = rowBase + rh*64 + ty*4 + r;
            size_t roff = (size_t)row * N;
#pragma unroll
            for (int ch = 0; ch < 2; ++ch) {
                int col = colBase + ch*64 + tx*4;
                float v0 = acc[rh*4+r][ch*4+0];
                float v1 = acc[rh*4+r][ch*4+1];
                float v2 = acc[rh*4+r][ch*4+2];
                float v3 = acc[rh*4+r][ch*4+3];
                if constexpr (ACC) {
                    float4 c = *(const float4*)&C[roff + col];
                    v0 += c.x; v1 += c.y; v2 += c.z; v3 += c.w;
                }
                if constexpr (HB) {
                    float4 bb = *(const float4*)&bias[col];
                    v0 += bb.x; v1 += bb.y; v2 += bb.z; v3 += bb.w;
                }
                if constexpr (RES) {
                    float4 rr = *(const float4*)&resid[roff + col];
                    v0 += rr.x; v1 += rr.y; v2 += rr.z; v3 += rr.w;
                }
                if constexpr (RELU) {
                    v0 = fmaxf(v0, 0.f); v1 = fmaxf(v1, 0.f);
                    v2 = fmaxf(v2, 0.f); v3 = fmaxf(v3, 0.f);
                }
                float4 ov; ov.x = v0; ov.y = v1; ov.z = v2; ov.w = v3;
                *(float4*)&C[roff + col] = ov;
            }
        }
    }
}

// ---------------------------------------------------------------------------
// LayerNorm over D=512, one wave per row (unchanged)
// ---------------------------------------------------------------------------
__global__ __launch_bounds__(64) void ln_kernel(
    const float* __restrict__ in, const float* __restrict__ sc,
    const float* __restrict__ bi, float* __restrict__ out)
{
    int row = blockIdx.x, lane = threadIdx.x;
    const float* r = in + (size_t)row * D_;
    float4 v0 = *(const float4*)&r[lane*8];
    float4 v1 = *(const float4*)&r[lane*8 + 4];
    float sum = v0.x+v0.y+v0.z+v0.w + v1.x+v1.y+v1.z+v1.w;
    float ss  = v0.x*v0.x+v0.y*v0.y+v0.z*v0.z+v0.w*v0.w
              + v1.x*v1.x+v1.y*v1.y+v1.z*v1.z+v1.w*v1.w;
#pragma unroll
    for (int o = 1; o < 64; o <<= 1) {
        sum += __shfl_xor(sum, o);
        ss  += __shfl_xor(ss, o);
    }
    float mean = sum * (1.f / D_);
    float var  = ss  * (1.f / D_) - mean * mean;
    float rstd = rsqrtf(var + 1e-5f);
    float4 s0 = *(const float4*)&sc[lane*8];
    float4 s1 = *(const float4*)&sc[lane*8 + 4];
    float4 b0 = *(const float4*)&bi[lane*8];
    float4 b1 = *(const float4*)&bi[lane*8 + 4];
    float* w = out + (size_t)row * D_;
    float4 o0, o1;
    o0.x = (v0.x-mean)*rstd*s0.x + b0.x; o0.y = (v0.y-mean)*rstd*s0.y + b0.y;
    o0.z = (v0.z-mean)*rstd*s0.z + b0.z; o0.w = (v0.w-mean)*rstd*s0.w + b0.w;
    o1.x = (v1.x-mean)*rstd*s1.x + b1.x; o1.y = (v1.y-mean)*rstd*s1.y + b1.y;
    o1.z = (v1.z-mean)*rstd*s1.z + b1.z; o1.w = (v1.w-mean)*rstd*s1.w + b1.w;
    *(float4*)&w[lane*8]     = o0;
    *(float4*)&w[lane*8 + 4] = o1;
}

// ---------------------------------------------------------------------------
// Fused causal attention v2.1, q==k. Block = (b, h, q-half): 512 blocks.
// Thread = (query row, d-half): q[32]+acc[32] in VGPRs.
// __launch_bounds__(512) WITHOUT min-occupancy arg: round-7 profile proved
// (512,4) capped VGPRs at 64 (HIP treats arg2 like CUDA min-blocks/CU) and
// spilled acc[] to scratch -> 654 MB of spill writes/dispatch. Plain (512)
// gave 120 VGPR + zero spill in v1.
// K/V in 64-row double-buffered LDS tiles (64 KB -> 2 blocks/CU possible).
// ---------------------------------------------------------------------------
#define QT_ 256
#define JT_ 64
__global__ __launch_bounds__(512) void attn_kernel(
    const float* __restrict__ qk, const float* __restrict__ vv,
    float* __restrict__ o)
{
    __shared__ float Ksh[2][JT_][DK_];   // 32 KB
    __shared__ float Vsh[2][JT_][DK_];   // 32 KB

    int blk = blockIdx.x;
    int qt  = blk & 1;                   // which 256-row query half
    int bh  = blk >> 1;
    int b = bh >> 3, h = bh & 7;
    const float* kbase = qk + (size_t)b * L_ * D_ + h * DK_;
    const float* vbase = vv + (size_t)b * L_ * D_ + h * DK_;
    int t   = threadIdx.x;
    int r   = qt * QT_ + (t >> 1);       // query row
    int dof = (t & 1) * 32;              // d-half offset

    // my q half (8 float4), pre-scaled by 1/sqrt(dk)
    float q[32];
    {
        const float* qrow = kbase + (size_t)r * D_ + dof;
#pragma unroll
        for (int c = 0; c < 8; ++c) {
            float4 v = *(const float4*)&qrow[c*4];
            q[c*4+0]=v.x*0.125f; q[c*4+1]=v.y*0.125f;
            q[c*4+2]=v.z*0.125f; q[c*4+3]=v.w*0.125f;
        }
    }
    float acc[32];
#pragma unroll
    for (int d = 0; d < 32; ++d) acc[d] = 0.f;
    float m = -3.0e38f, s = 0.f;

    // staging geometry: 1024 float4 per 64x64 tile, 2 per thread
    int f0 = t, f1 = 512 + t;
    int j0s = f0 >> 4, d0s = (f0 & 15) << 2;
    int j1s = f1 >> 4, d1s = (f1 & 15) << 2;

    const int ntiles = (qt + 1) * 4;     // 4 or 8 j-tiles

    // prologue: stage tile 0 into buf 0
    {
        *(float4*)&Ksh[0][j0s][d0s] = *(const float4*)&kbase[(size_t)j0s * D_ + d0s];
        *(float4*)&Ksh[0][j1s][d1s] = *(const float4*)&kbase[(size_t)j1s * D_ + d1s];
        *(float4*)&Vsh[0][j0s][d0s] = *(const float4*)&vbase[(size_t)j0s * D_ + d0s];
        *(float4*)&Vsh[0][j1s][d1s] = *(const float4*)&vbase[(size_t)j1s * D_ + d1s];
    }
    __syncthreads();

    for (int tile = 0; tile < ntiles; ++tile) {
        int cur = tile & 1;
        // T14: issue next tile's global loads BEFORE compute; write after
        float4 nk0, nk1, nv0, nv1;
        bool have_next = (tile + 1 < ntiles);
        if (have_next) {
            size_t jt1 = (size_t)(tile + 1) * JT_;
            nk0 = *(const float4*)&kbase[(jt1 + j0s) * D_ + d0s];
            nk1 = *(const float4*)&kbase[(jt1 + j1s) * D_ + d1s];
            nv0 = *(const float4*)&vbase[(jt1 + j0s) * D_ + d0s];
            nv1 = *(const float4*)&vbase[(jt1 + j1s) * D_ + d1s];
        }

        int jt = tile * JT_;
        int jmax = min(r, jt + JT_);     // strictly lower: j < r
        for (int jb = jt; jb < jmax; jb += 16) {
            float sc[16];
            float tmax = -3.0e38f;
#pragma unroll
            for (int jj = 0; jj < 16; ++jj) {
                const float* kr = &Ksh[cur][jb - jt + jj][dof];
                float d0 = 0.f, d1 = 0.f, d2 = 0.f, d3 = 0.f;
#pragma unroll
                for (int c = 0; c < 8; ++c) {
                    float4 kv = *(const float4*)&kr[c*4];
                    d0 += q[c*4+0]*kv.x; d1 += q[c*4+1]*kv.y;
                    d2 += q[c*4+2]*kv.z; d3 += q[c*4+3]*kv.w;
                }
                float hd = (d0 + d1) + (d2 + d3);
                float sv = hd + __shfl_xor(hd, 1);   // combine halves
                sv = (jb + jj < jmax) ? sv : -3.0e38f;
                sc[jj] = sv;
                tmax = fmaxf(tmax, sv);
            }
            float mnew = fmaxf(m, tmax);             // tmax finite (jj=0 valid)
            float cor  = __expf(m - mnew);
            s *= cor;
#pragma unroll
            for (int d = 0; d < 32; ++d) acc[d] *= cor;
#pragma unroll
            for (int jj = 0; jj < 16; ++jj) {
                float p = __expf(sc[jj] - mnew);     // masked -> 0
                s += p;
                const float* vr = &Vsh[cur][jb - jt + jj][dof];
#pragma unroll
                for (int c = 0; c < 8; ++c) {
                    float4 vw = *(const float4*)&vr[c*4];
                    acc[c*4+0] += p * vw.x; acc[c*4+1] += p * vw.y;
                    acc[c*4+2] += p * vw.z; acc[c*4+3] += p * vw.w;
                }
            }
            m = mnew;
        }

        if (have_next) {                 // write-late: lands before barrier
            int nxt = cur ^ 1;
            *(float4*)&Ksh[nxt][j0s][d0s] = nk0;
            *(float4*)&Ksh[nxt][j1s][d1s] = nk1;
            *(float4*)&Vsh[nxt][j0s][d0s] = nv0;
            *(float4*)&Vsh[nxt][j1s][d1s] = nv1;
        }
        __syncthreads();
    }

    float rs = (r > 0 && s > 0.f) ? (1.f / s) : 0.f;   // zero_pad row 0
    float* orow = o + ((size_t)b * L_ + r) * D_ + h * DK_ + dof;
#pragma unroll
    for (int c = 0; c < 8; ++c) {
        float4 w;
        w.x = acc[c*4+0]*rs; w.y = acc[c*4+1]*rs;
        w.z = acc[c*4+2]*rs; w.w = acc[c*4+3]*rs;
        *(float4*)&orow[c*4] = w;
    }
}

// ---------------------------------------------------------------------------
// Final logits: dot(h2[row], w3) + b3 -> sigmoid -> out (drop l==0)
// ---------------------------------------------------------------------------
__global__ __launch_bounds__(64) void head_out_kernel(
    const float* __restrict__ h2, const float* __restrict__ w3,
    const float* __restrict__ b3, float* __restrict__ out)
{
    int row = blockIdx.x, lane = threadIdx.x;
    float4 hv = *(const float4*)&h2[(size_t)row * FC2_ + lane*4];
    float4 wv = *(const float4*)&w3[lane*4];
    float d = hv.x*wv.x + hv.y*wv.y + hv.z*wv.z + hv.w*wv.w;
#pragma unroll
    for (int o = 1; o < 64; o <<= 1) d += __shfl_xor(d, o);
    if (lane == 0) {
        int l = row & (L_ - 1), b = row >> 9;
        if (l > 0) {
            float logit = d + b3[0];
            out[(size_t)b * (L_ - 1) + l - 1] = 1.f / (1.f + expf(-logit));
        }
    }
}

// ---------------------------------------------------------------------------
extern "C" void kernel_launch(void* const* d_in, const int* in_sizes, int n_in,
                              void* d_out, int out_size, void* d_ws, size_t ws_size,
                              hipStream_t stream)
{
    const int*   prob    = (const int*)d_in[0];
    const int*   corr    = (const int*)d_in[1];
    const float* q_embed = (const float*)d_in[2];
    const float* qa_emb  = (const float*)d_in[3];
    const float* q_diff  = (const float*)d_in[4];
    const float* dparam  = (const float*)d_in[5];
    const float* kw   = (const float*)d_in[6];
    const float* kb   = (const float*)d_in[7];
    const float* vw   = (const float*)d_in[8];
    const float* vb   = (const float*)d_in[9];
    const float* ow   = (const float*)d_in[10];
    const float* ob   = (const float*)d_in[11];
    const float* ln1s = (const float*)d_in[12];
    const float* ln1b = (const float*)d_in[13];
    const float* w1   = (const float*)d_in[14];
    const float* b1   = (const float*)d_in[15];
    const float* w2   = (const float*)d_in[16];
    const float* b2   = (const float*)d_in[17];
    const float* ln2s = (const float*)d_in[18];
    const float* ln2b = (const float*)d_in[19];
    const float* ow1  = (const float*)d_in[20];
    const float* ob1  = (const float*)d_in[21];
    const float* ow2  = (const float*)d_in[22];
    const float* ob2  = (const float*)d_in[23];
    const float* ow3  = (const float*)d_in[24];
    const float* ob3  = (const float*)d_in[25];
    float* out = (float*)d_out;

    const size_t SZ = (size_t)B_ * L_ * D_;     // 8.39M floats
    float* qe = (float*)d_ws;
    float* x  = qe + SZ;
    float* y  = x  + SZ;
    float* t0 = y  + SZ;
    float* t1 = t0 + SZ;
    float* t2 = t1 + SZ;
    float* t3 = t2 + SZ;                         // M x 256 (uses SZ/2)

    const int M = B_ * L_;                       // 16384
    dim3 g512(512 / 128, M / 128);
    dim3 g256(256 / 128, M / 128);

    embed_kernel<<<M, 256, 0, stream>>>(prob, corr, q_embed, qa_emb, q_diff, dparam,
                                        qe, x, y);

    for (int i = 0; i < NB_; ++i) {
        // qk = x@kw + kb   (q == k, single projection)
        gemm_kernel<true,false,false,false><<<g512, 256, 0, stream>>>(
            x, kw + (size_t)i*D_*D_, kb + i*D_, nullptr, t0, M, D_, D_);
        // v = y@vw + vb
        gemm_kernel<true,false,false,false><<<g512, 256, 0, stream>>>(
            y, vw + (size_t)i*D_*D_, vb + i*D_, nullptr, t1, M, D_, D_);
        // o = attn(qk, v)
        attn_kernel<<<B_*H_*2, 512, 0, stream>>>(t0, t1, t2);
        // t0 = x + o@ow + ob
        gemm_kernel<true,false,false,true><<<g512, 256, 0, stream>>>(
            t2, ow + (size_t)i*D_*D_, ob + i*D_, x, t0, M, D_, D_);
        // x = LN1(t0)
        ln_kernel<<<M, 64, 0, stream>>>(t0, ln1s + i*D_, ln1b + i*D_, x);
        // t3 = relu(x@w1 + b1)
        gemm_kernel<true,true,false,false><<<g256, 256, 0, stream>>>(
            x, w1 + (size_t)i*D_*DFF_, b1 + i*DFF_, nullptr, t3, M, DFF_, D_);
        // t2 = x + t3@w2 + b2
        gemm_kernel<true,false,false,true><<<g512, 256, 0, stream>>>(
            t3, w2 + (size_t)i*DFF_*D_, b2 + i*D_, x, t2, M, D_, DFF_);
        // x = LN2(t2)
        ln_kernel<<<M, 64, 0, stream>>>(t2, ln2s + i*D_, ln2b + i*D_, x);
    }

    // head: h1 = relu([x,qe]@ow1 + ob1) done as two GEMMs (split-K of concat)
    gemm_kernel<true,false,false,false><<<g512, 256, 0, stream>>>(
        x, ow1, ob1, nullptr, t0, M, FC1_, D_);
    gemm_kernel<false,true,true,false><<<g512, 256, 0, stream>>>(
        qe, ow1 + (size_t)D_*FC1_, nullptr, nullptr, t0, M, FC1_, D_);
    // h2 = relu(h1@ow2 + ob2)
    gemm_kernel<true,true,false,false><<<g256, 256, 0, stream>>>(
        t0, ow2, ob2, nullptr, t3, M, FC2_, FC1_);
    // logits + sigmoid + drop first position
    head_out_kernel<<<M, 64, 0, stream>>>(t3, ow3, ob3, out);
}

// Round 10
// 1339.108 us; speedup vs baseline: 1.7418x; 1.6116x over previous
//
#include <hip/hip_runtime.h>
#include <math.h>

#define B_   32
#define L_   512
#define D_   512
#define H_   8
#define DK_  64
#define NB_  2
#define DFF_ 256
#define NPID_ 10000
#define FC1_ 512
#define FC2_ 256

typedef __attribute__((ext_vector_type(8))) __bf16 bf16x8;
typedef __attribute__((ext_vector_type(4))) float f32x4;

// ---------------------------------------------------------------------------
// Embedding + cosine positional encoding (unchanged)
// ---------------------------------------------------------------------------
__global__ __launch_bounds__(256) void embed_kernel(
    const int* __restrict__ prob, const int* __restrict__ corr,
    const float* __restrict__ q_embed, const float* __restrict__ qa_embed,
    const float* __restrict__ q_diff, const float* __restrict__ dparam,
    float* __restrict__ qe, float* __restrict__ x, float* __restrict__ y)
{
    int bl = blockIdx.x;            // b*L + l
    int l  = bl & (L_ - 1);
    int q  = prob[bl] + 1;
    int qa = q + corr[bl] * NPID_;
    const float* qe_r = q_embed + (size_t)q  * D_;
    const float* qd_r = q_diff  + (size_t)q  * D_;
    const float* dp_r = dparam  + (size_t)q  * D_;
    const float* qa_r = qa_embed + (size_t)qa * D_;
    size_t ooff = (size_t)bl * D_;
    const float nl = -logf(10000.0f) / (float)D_;
    for (int d = threadIdx.x; d < D_; d += 256) {
        int   i2   = d & ~1;
        float freq = expf((float)i2 * nl);
        float arg  = (float)l * freq;
        float pe   = (d & 1) ? cosf(arg) : sinf(arg);
        float qev  = qe_r[d] + dp_r[d] * qd_r[d];
        qe[ooff + d] = qev;
        x [ooff + d] = qev + pe;
        y [ooff + d] = qa_r[d] + pe;
    }
}

// ---------------------------------------------------------------------------
// bf16-MFMA GEMM: C[M,N] = (ACC?C:0) + bf16(A)[M,K]@bf16(W)[K,N] (+bias)
// (+resid), opt ReLU. fp32 accumulate. 128x128 tile, BK=32, 256 thr = 4 waves
// (2x2), each wave 64x64 out = 4x4 mfma_f32_16x16x32_bf16 tiles.
// LDS: A and B both stored [dim][k] as bf16 pairs (u32 words), row stride
// 20 words (80B -> 16B-aligned granules), granule-XOR swizzle g^=(row>>3)&3
// applied identically on write and read (keeps writes <=4-way, reads ~2-way).
// Fragment layout (m89/m91-verified): A row & B col via lane&15,
// k=(lane>>4)*8+j; D col=lane&15, row=(lane>>4)*4+reg.
// NOTE: no 2nd __launch_bounds__ arg (round-7 lesson: it caps VGPRs hard).
// ---------------------------------------------------------------------------
__device__ inline unsigned pk2(float a, float b){
    __bf16 x = (__bf16)a, y = (__bf16)b;
    unsigned short xu = __builtin_bit_cast(unsigned short, x);
    unsigned short yu = __builtin_bit_cast(unsigned short, y);
    return (unsigned)xu | ((unsigned)yu << 16);
}
__device__ inline int woff(int r, int wk){    // word offset in [128][20] tile
    int g = wk >> 2, w = wk & 3;
    return r*20 + (((g ^ ((r>>3)&3)) << 2) | w);
}

template<bool HB, bool RELU, bool ACC, bool RES>
__global__ __launch_bounds__(256) void gemm_bf16_kernel(
    const float* __restrict__ A, const float* __restrict__ W,
    const float* __restrict__ bias, const float* __restrict__ resid,
    float* __restrict__ C, int M, int N, int K)
{
    __shared__ unsigned AsW[128*20];   // 10 KB
    __shared__ unsigned BsW[128*20];   // 10 KB
    int t = threadIdx.x;
    int l = t & 63, w = t >> 6;
    int rowBase = blockIdx.y*128, colBase = blockIdx.x*128;
    int ml = (w>>1)*64, nl = (w&1)*64;

    f32x4 acc[4][4];
#pragma unroll
    for (int i=0;i<4;++i)
#pragma unroll
        for (int j=0;j<4;++j) acc[i][j] = (f32x4){0.f,0.f,0.f,0.f};

    int arow = t>>1, awb = (t&1)*8;    // A staging: 2 thr/row, 8 words each
    int kp = t>>4,  nch = (t&15)*8;    // B staging: k-pair kp, 8 n values

    for (int k0 = 0; k0 < K; k0 += 32) {
        __syncthreads();
        // ---- stage A (128 x 32 fp32 -> bf16 pairs) ----
        const float* ap = A + (size_t)(rowBase + arow)*K + k0 + (t&1)*16;
        float4 a0 = *(const float4*)ap,     a1 = *(const float4*)(ap+4);
        float4 a2 = *(const float4*)(ap+8), a3 = *(const float4*)(ap+12);
        AsW[woff(arow, awb+0)] = pk2(a0.x,a0.y); AsW[woff(arow, awb+1)] = pk2(a0.z,a0.w);
        AsW[woff(arow, awb+2)] = pk2(a1.x,a1.y); AsW[woff(arow, awb+3)] = pk2(a1.z,a1.w);
        AsW[woff(arow, awb+4)] = pk2(a2.x,a2.y); AsW[woff(arow, awb+5)] = pk2(a2.z,a2.w);
        AsW[woff(arow, awb+6)] = pk2(a3.x,a3.y); AsW[woff(arow, awb+7)] = pk2(a3.z,a3.w);
        // ---- stage B transposed (32 x 128 fp32 -> [n][k] bf16 pairs) ----
        const float* b0p = W + (size_t)(k0 + 2*kp)*N + colBase + nch;
        const float* b1p = b0p + N;
        float4 w0a = *(const float4*)b0p, w0b = *(const float4*)(b0p+4);
        float4 w1a = *(const float4*)b1p, w1b = *(const float4*)(b1p+4);
        BsW[woff(nch+0, kp)] = pk2(w0a.x, w1a.x);
        BsW[woff(nch+1, kp)] = pk2(w0a.y, w1a.y);
        BsW[woff(nch+2, kp)] = pk2(w0a.z, w1a.z);
        BsW[woff(nch+3, kp)] = pk2(w0a.w, w1a.w);
        BsW[woff(nch+4, kp)] = pk2(w0b.x, w1b.x);
        BsW[woff(nch+5, kp)] = pk2(w0b.y, w1b.y);
        BsW[woff(nch+6, kp)] = pk2(w0b.z, w1b.z);
        BsW[woff(nch+7, kp)] = pk2(w0b.w, w1b.w);
        __syncthreads();

        // ---- fragments + 16 MFMA ----
        int kb4 = (l>>4)*4;            // granule base word
        bf16x8 af[4], bfr[4];
#pragma unroll
        for (int mt=0; mt<4; ++mt)
            af[mt] = *(const bf16x8*)((const char*)AsW + 4*woff(ml + mt*16 + (l&15), kb4));
#pragma unroll
        for (int nt=0; nt<4; ++nt)
            bfr[nt] = *(const bf16x8*)((const char*)BsW + 4*woff(nl + nt*16 + (l&15), kb4));
#pragma unroll
        for (int mt=0; mt<4; ++mt)
#pragma unroll
            for (int nt=0; nt<4; ++nt)
                acc[mt][nt] = __builtin_amdgcn_mfma_f32_16x16x32_bf16(
                                  af[mt], bfr[nt], acc[mt][nt], 0, 0, 0);
    }

    // ---- epilogue ----
    int cb = colBase + nl + (l&15);
    int rb = rowBase + ml + ((l>>4)<<2);
#pragma unroll
    for (int mt=0; mt<4; ++mt){
#pragma unroll
        for (int nt=0; nt<4; ++nt){
            int col = cb + nt*16;
            float bv = 0.f;
            if constexpr (HB) bv = bias[col];
#pragma unroll
            for (int r=0;r<4;++r){
                int row = rb + mt*16 + r;
                size_t off = (size_t)row*N + col;
                float v = acc[mt][nt][r] + bv;
                if constexpr (ACC) v += C[off];
                if constexpr (RES) v += resid[off];
                if constexpr (RELU) v = fmaxf(v, 0.f);
                C[off] = v;
            }
        }
    }
}

// ---------------------------------------------------------------------------
// LayerNorm over D=512, one wave per row (unchanged)
// ---------------------------------------------------------------------------
__global__ __launch_bounds__(64) void ln_kernel(
    const float* __restrict__ in, const float* __restrict__ sc,
    const float* __restrict__ bi, float* __restrict__ out)
{
    int row = blockIdx.x, lane = threadIdx.x;
    const float* r = in + (size_t)row * D_;
    float4 v0 = *(const float4*)&r[lane*8];
    float4 v1 = *(const float4*)&r[lane*8 + 4];
    float sum = v0.x+v0.y+v0.z+v0.w + v1.x+v1.y+v1.z+v1.w;
    float ss  = v0.x*v0.x+v0.y*v0.y+v0.z*v0.z+v0.w*v0.w
              + v1.x*v1.x+v1.y*v1.y+v1.z*v1.z+v1.w*v1.w;
#pragma unroll
    for (int o = 1; o < 64; o <<= 1) {
        sum += __shfl_xor(sum, o);
        ss  += __shfl_xor(ss, o);
    }
    float mean = sum * (1.f / D_);
    float var  = ss  * (1.f / D_) - mean * mean;
    float rstd = rsqrtf(var + 1e-5f);
    float4 s0 = *(const float4*)&sc[lane*8];
    float4 s1 = *(const float4*)&sc[lane*8 + 4];
    float4 b0 = *(const float4*)&bi[lane*8];
    float4 b1 = *(const float4*)&bi[lane*8 + 4];
    float* w = out + (size_t)row * D_;
    float4 o0, o1;
    o0.x = (v0.x-mean)*rstd*s0.x + b0.x; o0.y = (v0.y-mean)*rstd*s0.y + b0.y;
    o0.z = (v0.z-mean)*rstd*s0.z + b0.z; o0.w = (v0.w-mean)*rstd*s0.w + b0.w;
    o1.x = (v1.x-mean)*rstd*s1.x + b1.x; o1.y = (v1.y-mean)*rstd*s1.y + b1.y;
    o1.z = (v1.z-mean)*rstd*s1.z + b1.z; o1.w = (v1.w-mean)*rstd*s1.w + b1.w;
    *(float4*)&w[lane*8]     = o0;
    *(float4*)&w[lane*8 + 4] = o1;
}

// ---------------------------------------------------------------------------
// Fused causal attention v2.1 (unchanged from round 9: 368 us, LDS-issue-bound)
// ---------------------------------------------------------------------------
#define QT_ 256
#define JT_ 64
__global__ __launch_bounds__(512) void attn_kernel(
    const float* __restrict__ qk, const float* __restrict__ vv,
    float* __restrict__ o)
{
    __shared__ float Ksh[2][JT_][DK_];   // 32 KB
    __shared__ float Vsh[2][JT_][DK_];   // 32 KB

    int blk = blockIdx.x;
    int qt  = blk & 1;
    int bh  = blk >> 1;
    int b = bh >> 3, h = bh & 7;
    const float* kbase = qk + (size_t)b * L_ * D_ + h * DK_;
    const float* vbase = vv + (size_t)b * L_ * D_ + h * DK_;
    int t   = threadIdx.x;
    int r   = qt * QT_ + (t >> 1);
    int dof = (t & 1) * 32;

    float q[32];
    {
        const float* qrow = kbase + (size_t)r * D_ + dof;
#pragma unroll
        for (int c = 0; c < 8; ++c) {
            float4 v = *(const float4*)&qrow[c*4];
            q[c*4+0]=v.x*0.125f; q[c*4+1]=v.y*0.125f;
            q[c*4+2]=v.z*0.125f; q[c*4+3]=v.w*0.125f;
        }
    }
    float acc[32];
#pragma unroll
    for (int d = 0; d < 32; ++d) acc[d] = 0.f;
    float m = -3.0e38f, s = 0.f;

    int f0 = t, f1 = 512 + t;
    int j0s = f0 >> 4, d0s = (f0 & 15) << 2;
    int j1s = f1 >> 4, d1s = (f1 & 15) << 2;

    const int ntiles = (qt + 1) * 4;

    {
        *(float4*)&Ksh[0][j0s][d0s] = *(const float4*)&kbase[(size_t)j0s * D_ + d0s];
        *(float4*)&Ksh[0][j1s][d1s] = *(const float4*)&kbase[(size_t)j1s * D_ + d1s];
        *(float4*)&Vsh[0][j0s][d0s] = *(const float4*)&vbase[(size_t)j0s * D_ + d0s];
        *(float4*)&Vsh[0][j1s][d1s] = *(const float4*)&vbase[(size_t)j1s * D_ + d1s];
    }
    __syncthreads();

    for (int tile = 0; tile < ntiles; ++tile) {
        int cur = tile & 1;
        float4 nk0, nk1, nv0, nv1;
        bool have_next = (tile + 1 < ntiles);
        if (have_next) {
            size_t jt1 = (size_t)(tile + 1) * JT_;
            nk0 = *(const float4*)&kbase[(jt1 + j0s) * D_ + d0s];
            nk1 = *(const float4*)&kbase[(jt1 + j1s) * D_ + d1s];
            nv0 = *(const float4*)&vbase[(jt1 + j0s) * D_ + d0s];
            nv1 = *(const float4*)&vbase[(jt1 + j1s) * D_ + d1s];
        }

        int jt = tile * JT_;
        int jmax = min(r, jt + JT_);
        for (int jb = jt; jb < jmax; jb += 16) {
            float sc[16];
            float tmax = -3.0e38f;
#pragma unroll
            for (int jj = 0; jj < 16; ++jj) {
                const float* kr = &Ksh[cur][jb - jt + jj][dof];
                float d0 = 0.f, d1 = 0.f, d2 = 0.f, d3 = 0.f;
#pragma unroll
                for (int c = 0; c < 8; ++c) {
                    float4 kv = *(const float4*)&kr[c*4];
                    d0 += q[c*4+0]*kv.x; d1 += q[c*4+1]*kv.y;
                    d2 += q[c*4+2]*kv.z; d3 += q[c*4+3]*kv.w;
                }
                float hd = (d0 + d1) + (d2 + d3);
                float sv = hd + __shfl_xor(hd, 1);
                sv = (jb + jj < jmax) ? sv : -3.0e38f;
                sc[jj] = sv;
                tmax = fmaxf(tmax, sv);
            }
            float mnew = fmaxf(m, tmax);
            float cor  = __expf(m - mnew);
            s *= cor;
#pragma unroll
            for (int d = 0; d < 32; ++d) acc[d] *= cor;
#pragma unroll
            for (int jj = 0; jj < 16; ++jj) {
                float p = __expf(sc[jj] - mnew);
                s += p;
                const float* vr = &Vsh[cur][jb - jt + jj][dof];
#pragma unroll
                for (int c = 0; c < 8; ++c) {
                    float4 vw = *(const float4*)&vr[c*4];
                    acc[c*4+0] += p * vw.x; acc[c*4+1] += p * vw.y;
                    acc[c*4+2] += p * vw.z; acc[c*4+3] += p * vw.w;
                }
            }
            m = mnew;
        }

        if (have_next) {
            int nxt = cur ^ 1;
            *(float4*)&Ksh[nxt][j0s][d0s] = nk0;
            *(float4*)&Ksh[nxt][j1s][d1s] = nk1;
            *(float4*)&Vsh[nxt][j0s][d0s] = nv0;
            *(float4*)&Vsh[nxt][j1s][d1s] = nv1;
        }
        __syncthreads();
    }

    float rs = (r > 0 && s > 0.f) ? (1.f / s) : 0.f;
    float* orow = o + ((size_t)b * L_ + r) * D_ + h * DK_ + dof;
#pragma unroll
    for (int c = 0; c < 8; ++c) {
        float4 w;
        w.x = acc[c*4+0]*rs; w.y = acc[c*4+1]*rs;
        w.z = acc[c*4+2]*rs; w.w = acc[c*4+3]*rs;
        *(float4*)&orow[c*4] = w;
    }
}

// ---------------------------------------------------------------------------
// Final logits: dot(h2[row], w3) + b3 -> sigmoid -> out (drop l==0)
// ---------------------------------------------------------------------------
__global__ __launch_bounds__(64) void head_out_kernel(
    const float* __restrict__ h2, const float* __restrict__ w3,
    const float* __restrict__ b3, float* __restrict__ out)
{
    int row = blockIdx.x, lane = threadIdx.x;
    float4 hv = *(const float4*)&h2[(size_t)row * FC2_ + lane*4];
    float4 wv = *(const float4*)&w3[lane*4];
    float d = hv.x*wv.x + hv.y*wv.y + hv.z*wv.z + hv.w*wv.w;
#pragma unroll
    for (int o = 1; o < 64; o <<= 1) d += __shfl_xor(d, o);
    if (lane == 0) {
        int l = row & (L_ - 1), b = row >> 9;
        if (l > 0) {
            float logit = d + b3[0];
            out[(size_t)b * (L_ - 1) + l - 1] = 1.f / (1.f + expf(-logit));
        }
    }
}

// ---------------------------------------------------------------------------
extern "C" void kernel_launch(void* const* d_in, const int* in_sizes, int n_in,
                              void* d_out, int out_size, void* d_ws, size_t ws_size,
                              hipStream_t stream)
{
    const int*   prob    = (const int*)d_in[0];
    const int*   corr    = (const int*)d_in[1];
    const float* q_embed = (const float*)d_in[2];
    const float* qa_emb  = (const float*)d_in[3];
    const float* q_diff  = (const float*)d_in[4];
    const float* dparam  = (const float*)d_in[5];
    const float* kw   = (const float*)d_in[6];
    const float* kb   = (const float*)d_in[7];
    const float* vw   = (const float*)d_in[8];
    const float* vb   = (const float*)d_in[9];
    const float* ow   = (const float*)d_in[10];
    const float* ob   = (const float*)d_in[11];
    const float* ln1s = (const float*)d_in[12];
    const float* ln1b = (const float*)d_in[13];
    const float* w1   = (const float*)d_in[14];
    const float* b1   = (const float*)d_in[15];
    const float* w2   = (const float*)d_in[16];
    const float* b2   = (const float*)d_in[17];
    const float* ln2s = (const float*)d_in[18];
    const float* ln2b = (const float*)d_in[19];
    const float* ow1  = (const float*)d_in[20];
    const float* ob1  = (const float*)d_in[21];
    const float* ow2  = (const float*)d_in[22];
    const float* ob2  = (const float*)d_in[23];
    const float* ow3  = (const float*)d_in[24];
    const float* ob3  = (const float*)d_in[25];
    float* out = (float*)d_out;

    const size_t SZ = (size_t)B_ * L_ * D_;     // 8.39M floats
    float* qe = (float*)d_ws;
    float* x  = qe + SZ;
    float* y  = x  + SZ;
    float* t0 = y  + SZ;
    float* t1 = t0 + SZ;
    float* t2 = t1 + SZ;
    float* t3 = t2 + SZ;                         // M x 256 (uses SZ/2)

    const int M = B_ * L_;                       // 16384
    dim3 g512(512 / 128, M / 128);
    dim3 g256(256 / 128, M / 128);

    embed_kernel<<<M, 256, 0, stream>>>(prob, corr, q_embed, qa_emb, q_diff, dparam,
                                        qe, x, y);

    for (int i = 0; i < NB_; ++i) {
        // qk = x@kw + kb   (q == k, single projection)
        gemm_bf16_kernel<true,false,false,false><<<g512, 256, 0, stream>>>(
            x, kw + (size_t)i*D_*D_, kb + i*D_, nullptr, t0, M, D_, D_);
        // v = y@vw + vb
        gemm_bf16_kernel<true,false,false,false><<<g512, 256, 0, stream>>>(
            y, vw + (size_t)i*D_*D_, vb + i*D_, nullptr, t1, M, D_, D_);
        // o = attn(qk, v)
        attn_kernel<<<B_*H_*2, 512, 0, stream>>>(t0, t1, t2);
        // t0 = x + o@ow + ob
        gemm_bf16_kernel<true,false,false,true><<<g512, 256, 0, stream>>>(
            t2, ow + (size_t)i*D_*D_, ob + i*D_, x, t0, M, D_, D_);
        // x = LN1(t0)
        ln_kernel<<<M, 64, 0, stream>>>(t0, ln1s + i*D_, ln1b + i*D_, x);
        // t3 = relu(x@w1 + b1)
        gemm_bf16_kernel<true,true,false,false><<<g256, 256, 0, stream>>>(
            x, w1 + (size_t)i*D_*DFF_, b1 + i*DFF_, nullptr, t3, M, DFF_, D_);
        // t2 = x + t3@w2 + b2
        gemm_bf16_kernel<true,false,false,true><<<g512, 256, 0, stream>>>(
            t3, w2 + (size_t)i*DFF_*D_, b2 + i*D_, x, t2, M, D_, DFF_);
        // x = LN2(t2)
        ln_kernel<<<M, 64, 0, stream>>>(t2, ln2s + i*D_, ln2b + i*D_, x);
    }

    // head: h1 = relu([x,qe]@ow1 + ob1) done as two GEMMs (split-K of concat)
    gemm_bf16_kernel<true,false,false,false><<<g512, 256, 0, stream>>>(
        x, ow1, ob1, nullptr, t0, M, FC1_, D_);
    gemm_bf16_kernel<false,true,true,false><<<g512, 256, 0, stream>>>(
        qe, ow1 + (size_t)D_*FC1_, nullptr, nullptr, t0, M, FC1_, D_);
    // h2 = relu(h1@ow2 + ob2)
    gemm_bf16_kernel<true,true,false,false><<<g256, 256, 0, stream>>>(
        t0, ow2, ob2, nullptr, t3, M, FC2_, FC1_);
    // logits + sigmoid + drop first position
    head_out_kernel<<<M, 64, 0, stream>>>(t3, ow3, ob3, out);
}

// Round 12
// 772.286 us; speedup vs baseline: 3.0201x; 1.7340x over previous
//
#include <hip/hip_runtime.h>
#include <math.h>

#define B_   32
#define L_   512
#define D_   512
#define H_   8
#define DK_  64
#define NB_  2
#define DFF_ 256
#define NPID_ 10000
#define FC1_ 512
#define FC2_ 256

typedef __attribute__((ext_vector_type(8))) __bf16 bf16x8;
typedef __attribute__((ext_vector_type(4))) float f32x4;

__device__ inline unsigned pk2(float a, float b){
    __bf16 x = (__bf16)a, y = (__bf16)b;
    unsigned short xu = __builtin_bit_cast(unsigned short, x);
    unsigned short yu = __builtin_bit_cast(unsigned short, y);
    return (unsigned)xu | ((unsigned)yu << 16);
}

// ---------------------------------------------------------------------------
// Embedding + cosine positional encoding (unchanged)
// ---------------------------------------------------------------------------
__global__ __launch_bounds__(256) void embed_kernel(
    const int* __restrict__ prob, const int* __restrict__ corr,
    const float* __restrict__ q_embed, const float* __restrict__ qa_embed,
    const float* __restrict__ q_diff, const float* __restrict__ dparam,
    float* __restrict__ qe, float* __restrict__ x, float* __restrict__ y)
{
    int bl = blockIdx.x;
    int l  = bl & (L_ - 1);
    int q  = prob[bl] + 1;
    int qa = q + corr[bl] * NPID_;
    const float* qe_r = q_embed + (size_t)q  * D_;
    const float* qd_r = q_diff  + (size_t)q  * D_;
    const float* dp_r = dparam  + (size_t)q  * D_;
    const float* qa_r = qa_embed + (size_t)qa * D_;
    size_t ooff = (size_t)bl * D_;
    const float nl = -logf(10000.0f) / (float)D_;
    for (int d = threadIdx.x; d < D_; d += 256) {
        int   i2   = d & ~1;
        float freq = expf((float)i2 * nl);
        float arg  = (float)l * freq;
        float pe   = (d & 1) ? cosf(arg) : sinf(arg);
        float qev  = qe_r[d] + dp_r[d] * qd_r[d];
        qe[ooff + d] = qev;
        x [ooff + d] = qev + pe;
        y [ooff + d] = qa_r[d] + pe;
    }
}

// ---------------------------------------------------------------------------
// bf16-MFMA GEMM (unchanged from round 10: validated, absmax 3.9e-3)
// ---------------------------------------------------------------------------
__device__ inline int woff(int r, int wk){
    int g = wk >> 2, w = wk & 3;
    return r*20 + (((g ^ ((r>>3)&3)) << 2) | w);
}

template<bool HB, bool RELU, bool ACC, bool RES>
__global__ __launch_bounds__(256) void gemm_bf16_kernel(
    const float* __restrict__ A, const float* __restrict__ W,
    const float* __restrict__ bias, const float* __restrict__ resid,
    float* __restrict__ C, int M, int N, int K)
{
    __shared__ unsigned AsW[128*20];
    __shared__ unsigned BsW[128*20];
    int t = threadIdx.x;
    int l = t & 63, w = t >> 6;
    int rowBase = blockIdx.y*128, colBase = blockIdx.x*128;
    int ml = (w>>1)*64, nl = (w&1)*64;

    f32x4 acc[4][4];
#pragma unroll
    for (int i=0;i<4;++i)
#pragma unroll
        for (int j=0;j<4;++j) acc[i][j] = (f32x4){0.f,0.f,0.f,0.f};

    int arow = t>>1, awb = (t&1)*8;
    int kp = t>>4,  nch = (t&15)*8;

    for (int k0 = 0; k0 < K; k0 += 32) {
        __syncthreads();
        const float* ap = A + (size_t)(rowBase + arow)*K + k0 + (t&1)*16;
        float4 a0 = *(const float4*)ap,     a1 = *(const float4*)(ap+4);
        float4 a2 = *(const float4*)(ap+8), a3 = *(const float4*)(ap+12);
        AsW[woff(arow, awb+0)] = pk2(a0.x,a0.y); AsW[woff(arow, awb+1)] = pk2(a0.z,a0.w);
        AsW[woff(arow, awb+2)] = pk2(a1.x,a1.y); AsW[woff(arow, awb+3)] = pk2(a1.z,a1.w);
        AsW[woff(arow, awb+4)] = pk2(a2.x,a2.y); AsW[woff(arow, awb+5)] = pk2(a2.z,a2.w);
        AsW[woff(arow, awb+6)] = pk2(a3.x,a3.y); AsW[woff(arow, awb+7)] = pk2(a3.z,a3.w);
        const float* b0p = W + (size_t)(k0 + 2*kp)*N + colBase + nch;
        const float* b1p = b0p + N;
        float4 w0a = *(const float4*)b0p, w0b = *(const float4*)(b0p+4);
        float4 w1a = *(const float4*)b1p, w1b = *(const float4*)(b1p+4);
        BsW[woff(nch+0, kp)] = pk2(w0a.x, w1a.x);
        BsW[woff(nch+1, kp)] = pk2(w0a.y, w1a.y);
        BsW[woff(nch+2, kp)] = pk2(w0a.z, w1a.z);
        BsW[woff(nch+3, kp)] = pk2(w0a.w, w1a.w);
        BsW[woff(nch+4, kp)] = pk2(w0b.x, w1b.x);
        BsW[woff(nch+5, kp)] = pk2(w0b.y, w1b.y);
        BsW[woff(nch+6, kp)] = pk2(w0b.z, w1b.z);
        BsW[woff(nch+7, kp)] = pk2(w0b.w, w1b.w);
        __syncthreads();

        int kb4 = (l>>4)*4;
        bf16x8 af[4], bfr[4];
#pragma unroll
        for (int mt=0; mt<4; ++mt)
            af[mt] = *(const bf16x8*)((const char*)AsW + 4*woff(ml + mt*16 + (l&15), kb4));
#pragma unroll
        for (int nt=0; nt<4; ++nt)
            bfr[nt] = *(const bf16x8*)((const char*)BsW + 4*woff(nl + nt*16 + (l&15), kb4));
#pragma unroll
        for (int mt=0; mt<4; ++mt)
#pragma unroll
            for (int nt=0; nt<4; ++nt)
                acc[mt][nt] = __builtin_amdgcn_mfma_f32_16x16x32_bf16(
                                  af[mt], bfr[nt], acc[mt][nt], 0, 0, 0);
    }

    int cb = colBase + nl + (l&15);
    int rb = rowBase + ml + ((l>>4)<<2);
#pragma unroll
    for (int mt=0; mt<4; ++mt){
#pragma unroll
        for (int nt=0; nt<4; ++nt){
            int col = cb + nt*16;
            float bv = 0.f;
            if constexpr (HB) bv = bias[col];
#pragma unroll
            for (int r=0;r<4;++r){
                int row = rb + mt*16 + r;
                size_t off = (size_t)row*N + col;
                float v = acc[mt][nt][r] + bv;
                if constexpr (ACC) v += C[off];
                if constexpr (RES) v += resid[off];
                if constexpr (RELU) v = fmaxf(v, 0.f);
                C[off] = v;
            }
        }
    }
}

// ---------------------------------------------------------------------------
// LayerNorm (unchanged)
// ---------------------------------------------------------------------------
__global__ __launch_bounds__(64) void ln_kernel(
    const float* __restrict__ in, const float* __restrict__ sc,
    const float* __restrict__ bi, float* __restrict__ out)
{
    int row = blockIdx.x, lane = threadIdx.x;
    const float* r = in + (size_t)row * D_;
    float4 v0 = *(const float4*)&r[lane*8];
    float4 v1 = *(const float4*)&r[lane*8 + 4];
    float sum = v0.x+v0.y+v0.z+v0.w + v1.x+v1.y+v1.z+v1.w;
    float ss  = v0.x*v0.x+v0.y*v0.y+v0.z*v0.z+v0.w*v0.w
              + v1.x*v1.x+v1.y*v1.y+v1.z*v1.z+v1.w*v1.w;
#pragma unroll
    for (int o = 1; o < 64; o <<= 1) {
        sum += __shfl_xor(sum, o);
        ss  += __shfl_xor(ss, o);
    }
    float mean = sum * (1.f / D_);
    float var  = ss  * (1.f / D_) - mean * mean;
    float rstd = rsqrtf(var + 1e-5f);
    float4 s0 = *(const float4*)&sc[lane*8];
    float4 s1 = *(const float4*)&sc[lane*8 + 4];
    float4 b0 = *(const float4*)&bi[lane*8];
    float4 b1 = *(const float4*)&bi[lane*8 + 4];
    float* w = out + (size_t)row * D_;
    float4 o0, o1;
    o0.x = (v0.x-mean)*rstd*s0.x + b0.x; o0.y = (v0.y-mean)*rstd*s0.y + b0.y;
    o0.z = (v0.z-mean)*rstd*s0.z + b0.z; o0.w = (v0.w-mean)*rstd*s0.w + b0.w;
    o1.x = (v1.x-mean)*rstd*s1.x + b1.x; o1.y = (v1.y-mean)*rstd*s1.y + b1.y;
    o1.z = (v1.z-mean)*rstd*s1.z + b1.z; o1.w = (v1.w-mean)*rstd*s1.w + b1.w;
    *(float4*)&w[lane*8]     = o0;
    *(float4*)&w[lane*8 + 4] = o1;
}

// ---------------------------------------------------------------------------
// MFMA fused causal attention, q==k. Block = (b,h,q-128-tile): 1024 blocks,
// 4 waves x 32 q-rows. Swapped S^T = K.Q^T (Q in regs as B-frags), online
// softmax per lane (m,l per ci), P via per-wave swizzled LDS round-trip,
// PV as O^T = V_T.P^T. K and V_T staged bf16, double-buffered, stride-36.
// Fragment layouts identical to the hardware-validated gemm_bf16_kernel.
// Audit notes (r11): only global row 0 can be all-masked with m=-inf
// (exp(0)=1 garbage) -> killed by rs=0 zero_pad; partially-live rows get
// finite mnew so masked lanes contribute exp(-3e38-finite)=0.
// ---------------------------------------------------------------------------
__global__ __launch_bounds__(256) void attn_mfma_kernel(
    const float* __restrict__ qk, const float* __restrict__ vv,
    float* __restrict__ o)
{
    __shared__ unsigned Ksh[2*64*36];   // [buf][j][36w] bf16 pairs along d
    __shared__ unsigned Vsh[2*64*36];   // [buf][d][36w] bf16 pairs along j (V^T)
    __shared__ unsigned Psh[4*32*32];   // per-wave [i32][32w], granule16-XOR swz

    const int tid  = threadIdx.x;
    const int w    = tid >> 6;
    const int lane = tid & 63;
    const int g    = lane >> 4;          // 0..3
    const int ln   = lane & 15;

    const int blk = blockIdx.x;
    const int qb  = blk & 3;
    const int bh  = blk >> 2;
    const int b   = bh >> 3, h = bh & 7;
    const float* kb = qk + (size_t)b * L_ * D_ + h * DK_;
    const float* vb = vv + (size_t)b * L_ * D_ + h * DK_;

    const int wimin = qb*128 + w*32;     // wave's first q row
    const int nt    = qb*2 + 2;          // j-tiles this block stages

    // Q fragments (B-operand of K.Q^T), pre-scaled by 1/sqrt(dk)=0.125
    bf16x8 qf[2][2];
#pragma unroll
    for (int ci=0; ci<2; ++ci){
        const float* qr = kb + (size_t)(wimin + ci*16 + ln) * D_ + g*8;
#pragma unroll
        for (int ks=0; ks<2; ++ks){
            float4 x0 = *(const float4*)(qr + ks*32);
            float4 x1 = *(const float4*)(qr + ks*32 + 4);
            uint4 u;
            u.x = pk2(x0.x*0.125f, x0.y*0.125f);
            u.y = pk2(x0.z*0.125f, x0.w*0.125f);
            u.z = pk2(x1.x*0.125f, x1.y*0.125f);
            u.w = pk2(x1.z*0.125f, x1.w*0.125f);
            qf[ci][ks] = __builtin_bit_cast(bf16x8, u);
        }
    }

    f32x4 acc_o[4][2];
#pragma unroll
    for (int dt=0;dt<4;++dt)
#pragma unroll
        for (int ci=0;ci<2;++ci) acc_o[dt][ci] = (f32x4){0.f,0.f,0.f,0.f};
    float m[2] = {-3.0e38f,-3.0e38f}, l[2] = {0.f,0.f};

    // staging geometry
    const int sj  = tid >> 2;            // K: j row 0..63
    const int sdc = tid & 3;             // K: d-chunk of 16
    const int vjp = tid & 31;            // V: j-pair 0..31
    const int vd2 = tid >> 5;            // V: d-chunk base 0..7 (handles +0,+8)

    // prologue: stage tile 0 -> buf 0
    {
        const float* kr = kb + (size_t)sj * D_ + sdc*16;
        float4 k0=*(const float4*)kr, k1=*(const float4*)(kr+4),
               k2=*(const float4*)(kr+8), k3=*(const float4*)(kr+12);
        uint4 wa = {pk2(k0.x,k0.y),pk2(k0.z,k0.w),pk2(k1.x,k1.y),pk2(k1.z,k1.w)};
        uint4 wb = {pk2(k2.x,k2.y),pk2(k2.z,k2.w),pk2(k3.x,k3.y),pk2(k3.z,k3.w)};
        *(uint4*)&Ksh[sj*36 + sdc*8]     = wa;
        *(uint4*)&Ksh[sj*36 + sdc*8 + 4] = wb;
#pragma unroll
        for (int hd=0; hd<2; ++hd){
            int dc = vd2 + hd*8;
            const float* v0 = vb + (size_t)(2*vjp)   * D_ + dc*4;
            const float* v1 = vb + (size_t)(2*vjp+1) * D_ + dc*4;
            float4 r0 = *(const float4*)v0, r1 = *(const float4*)v1;
            Vsh[(dc*4+0)*36 + vjp] = pk2(r0.x, r1.x);
            Vsh[(dc*4+1)*36 + vjp] = pk2(r0.y, r1.y);
            Vsh[(dc*4+2)*36 + vjp] = pk2(r0.z, r1.z);
            Vsh[(dc*4+3)*36 + vjp] = pk2(r0.w, r1.w);
        }
    }
    __syncthreads();

    for (int t = 0; t < nt; ++t) {
        const int cur = t & 1;
        const unsigned* Kc = Ksh + cur*2304;
        const unsigned* Vc = Vsh + cur*2304;

        // T14: issue next tile's global loads before compute
        float4 nk0,nk1,nk2,nk3, nva0,nva1,nvb0,nvb1;
        const bool have_next = (t+1 < nt);
        if (have_next) {
            size_t jg = (size_t)(t+1)*64;
            const float* kr = kb + (jg + sj)*D_ + sdc*16;
            nk0=*(const float4*)kr;     nk1=*(const float4*)(kr+4);
            nk2=*(const float4*)(kr+8); nk3=*(const float4*)(kr+12);
            const float* v0 = vb + (jg + 2*vjp)*D_;
            const float* v1 = vb + (jg + 2*vjp+1)*D_;
            nva0=*(const float4*)(v0 + vd2*4);     nva1=*(const float4*)(v1 + vd2*4);
            nvb0=*(const float4*)(v0 + (vd2+8)*4); nvb1=*(const float4*)(v1 + (vd2+8)*4);
        }

        const int jbase = t*64;
        if (jbase <= wimin + 30) {       // wave has live rows in this tile
            // ---- S^T = K . Q^T : 8 A-frags, 16 mfma ----
            f32x4 s[4][2];
#pragma unroll
            for (int jt=0;jt<4;++jt)
#pragma unroll
                for (int ci=0;ci<2;++ci) s[jt][ci]=(f32x4){0.f,0.f,0.f,0.f};
#pragma unroll
            for (int ks=0; ks<2; ++ks){
#pragma unroll
                for (int jt=0; jt<4; ++jt){
                    bf16x8 ak = __builtin_bit_cast(bf16x8,
                        *(const uint4*)&Kc[(jt*16 + ln)*36 + ks*16 + g*4]);
#pragma unroll
                    for (int ci=0; ci<2; ++ci)
                        s[jt][ci] = __builtin_amdgcn_mfma_f32_16x16x32_bf16(
                                        ak, qf[ci][ks], s[jt][ci], 0,0,0);
                }
            }

            const bool tail = (jbase + 63 >= wimin);
#pragma unroll
            for (int ci=0; ci<2; ++ci){
                const int ig = wimin + ci*16 + ln;
                float p[4][4];
                float tmax = -3.0e38f;
#pragma unroll
                for (int jt=0;jt<4;++jt)
#pragma unroll
                    for (int r=0;r<4;++r){
                        float sv = s[jt][ci][r];
                        if (tail) {
                            int jgl = jbase + jt*16 + g*4 + r;
                            if (jgl >= ig) sv = -3.0e38f;   // strict j < i
                        }
                        p[jt][r] = sv;
                        tmax = fmaxf(tmax, sv);
                    }
                tmax = fmaxf(tmax, __shfl_xor(tmax,16));
                tmax = fmaxf(tmax, __shfl_xor(tmax,32));
                float mnew = fmaxf(m[ci], tmax);
                float cor  = __expf(m[ci] - mnew);
                m[ci] = mnew;
                float ps = 0.f;
#pragma unroll
                for (int jt=0;jt<4;++jt)
#pragma unroll
                    for (int r=0;r<4;++r){
                        float e = __expf(p[jt][r] - mnew);
                        p[jt][r] = e; ps += e;
                    }
                ps += __shfl_xor(ps,16);
                ps += __shfl_xor(ps,32);
                l[ci] = l[ci]*cor + ps;
#pragma unroll
                for (int dt=0;dt<4;++dt) acc_o[dt][ci] *= cor;
                // P -> per-wave LDS [i32][j] bf16, granule16 XOR (i32&7)
                int i32 = ci*16 + ln;
                unsigned pbase = w*1024 + i32*32;
#pragma unroll
                for (int jt=0;jt<4;++jt){
                    int grs = (jt*2 + (g>>1)) ^ (i32 & 7);
                    uint2 pw;
                    pw.x = pk2(p[jt][0], p[jt][1]);
                    pw.y = pk2(p[jt][2], p[jt][3]);
                    *(uint2*)&Psh[pbase + grs*4 + (g&1)*2] = pw;
                }
            }

            // ---- O^T += V_T . P^T : 16 mfma ----
#pragma unroll
            for (int ks2=0; ks2<2; ++ks2){
                bf16x8 pb[2];
#pragma unroll
                for (int ci=0; ci<2; ++ci){
                    int i32 = ci*16 + ln;
                    int grs = (ks2*4 + g) ^ (i32 & 7);
                    pb[ci] = __builtin_bit_cast(bf16x8,
                        *(const uint4*)&Psh[w*1024 + i32*32 + grs*4]);
                }
#pragma unroll
                for (int dt=0; dt<4; ++dt){
                    bf16x8 av = __builtin_bit_cast(bf16x8,
                        *(const uint4*)&Vc[(dt*16 + ln)*36 + ks2*16 + g*4]);
#pragma unroll
                    for (int ci=0; ci<2; ++ci)
                        acc_o[dt][ci] = __builtin_amdgcn_mfma_f32_16x16x32_bf16(
                                            av, pb[ci], acc_o[dt][ci], 0,0,0);
                }
            }
        }

        // write-late staging of next tile
        if (have_next) {
            unsigned* Kn = Ksh + (cur^1)*2304;
            unsigned* Vn = Vsh + (cur^1)*2304;
            uint4 wa = {pk2(nk0.x,nk0.y),pk2(nk0.z,nk0.w),pk2(nk1.x,nk1.y),pk2(nk1.z,nk1.w)};
            uint4 wb = {pk2(nk2.x,nk2.y),pk2(nk2.z,nk2.w),pk2(nk3.x,nk3.y),pk2(nk3.z,nk3.w)};
            *(uint4*)&Kn[sj*36 + sdc*8]     = wa;
            *(uint4*)&Kn[sj*36 + sdc*8 + 4] = wb;
            int dc0 = vd2, dc1 = vd2+8;
            Vn[(dc0*4+0)*36 + vjp] = pk2(nva0.x, nva1.x);
            Vn[(dc0*4+1)*36 + vjp] = pk2(nva0.y, nva1.y);
            Vn[(dc0*4+2)*36 + vjp] = pk2(nva0.z, nva1.z);
            Vn[(dc0*4+3)*36 + vjp] = pk2(nva0.w, nva1.w);
            Vn[(dc1*4+0)*36 + vjp] = pk2(nvb0.x, nvb1.x);
            Vn[(dc1*4+1)*36 + vjp] = pk2(nvb0.y, nvb1.y);
            Vn[(dc1*4+2)*36 + vjp] = pk2(nvb0.z, nvb1.z);
            Vn[(dc1*4+3)*36 + vjp] = pk2(nvb0.w, nvb1.w);
        }
        __syncthreads();
    }

    // epilogue: O[i][d] = O^T/l  (zero_pad row 0 via rs=0)
#pragma unroll
    for (int ci=0; ci<2; ++ci){
        int ig = wimin + ci*16 + ln;
        float rs = (ig > 0 && l[ci] > 0.f) ? (1.f / l[ci]) : 0.f;
        float* orow = o + ((size_t)b * L_ + ig) * D_ + h * DK_;
#pragma unroll
        for (int dt=0; dt<4; ++dt){
            float4 ov;
            ov.x = acc_o[dt][ci][0]*rs; ov.y = acc_o[dt][ci][1]*rs;
            ov.z = acc_o[dt][ci][2]*rs; ov.w = acc_o[dt][ci][3]*rs;
            *(float4*)&orow[dt*16 + g*4] = ov;
        }
    }
}

// ---------------------------------------------------------------------------
// Final logits (unchanged)
// ---------------------------------------------------------------------------
__global__ __launch_bounds__(64) void head_out_kernel(
    const float* __restrict__ h2, const float* __restrict__ w3,
    const float* __restrict__ b3, float* __restrict__ out)
{
    int row = blockIdx.x, lane = threadIdx.x;
    float4 hv = *(const float4*)&h2[(size_t)row * FC2_ + lane*4];
    float4 wv = *(const float4*)&w3[lane*4];
    float d = hv.x*wv.x + hv.y*wv.y + hv.z*wv.z + hv.w*wv.w;
#pragma unroll
    for (int o = 1; o < 64; o <<= 1) d += __shfl_xor(d, o);
    if (lane == 0) {
        int l = row & (L_ - 1), b = row >> 9;
        if (l > 0) {
            float logit = d + b3[0];
            out[(size_t)b * (L_ - 1) + l - 1] = 1.f / (1.f + expf(-logit));
        }
    }
}

// ---------------------------------------------------------------------------
extern "C" void kernel_launch(void* const* d_in, const int* in_sizes, int n_in,
                              void* d_out, int out_size, void* d_ws, size_t ws_size,
                              hipStream_t stream)
{
    const int*   prob    = (const int*)d_in[0];
    const int*   corr    = (const int*)d_in[1];
    const float* q_embed = (const float*)d_in[2];
    const float* qa_emb  = (const float*)d_in[3];
    const float* q_diff  = (const float*)d_in[4];
    const float* dparam  = (const float*)d_in[5];
    const float* kw   = (const float*)d_in[6];
    const float* kb   = (const float*)d_in[7];
    const float* vw   = (const float*)d_in[8];
    const float* vb   = (const float*)d_in[9];
    const float* ow   = (const float*)d_in[10];
    const float* ob   = (const float*)d_in[11];
    const float* ln1s = (const float*)d_in[12];
    const float* ln1b = (const float*)d_in[13];
    const float* w1   = (const float*)d_in[14];
    const float* b1   = (const float*)d_in[15];
    const float* w2   = (const float*)d_in[16];
    const float* b2   = (const float*)d_in[17];
    const float* ln2s = (const float*)d_in[18];
    const float* ln2b = (const float*)d_in[19];
    const float* ow1  = (const float*)d_in[20];
    const float* ob1  = (const float*)d_in[21];
    const float* ow2  = (const float*)d_in[22];
    const float* ob2  = (const float*)d_in[23];
    const float* ow3  = (const float*)d_in[24];
    const float* ob3  = (const float*)d_in[25];
    float* out = (float*)d_out;

    const size_t SZ = (size_t)B_ * L_ * D_;
    float* qe = (float*)d_ws;
    float* x  = qe + SZ;
    float* y  = x  + SZ;
    float* t0 = y  + SZ;
    float* t1 = t0 + SZ;
    float* t2 = t1 + SZ;
    float* t3 = t2 + SZ;

    const int M = B_ * L_;
    dim3 g512(512 / 128, M / 128);
    dim3 g256(256 / 128, M / 128);

    embed_kernel<<<M, 256, 0, stream>>>(prob, corr, q_embed, qa_emb, q_diff, dparam,
                                        qe, x, y);

    for (int i = 0; i < NB_; ++i) {
        gemm_bf16_kernel<true,false,false,false><<<g512, 256, 0, stream>>>(
            x, kw + (size_t)i*D_*D_, kb + i*D_, nullptr, t0, M, D_, D_);
        gemm_bf16_kernel<true,false,false,false><<<g512, 256, 0, stream>>>(
            y, vw + (size_t)i*D_*D_, vb + i*D_, nullptr, t1, M, D_, D_);
        attn_mfma_kernel<<<B_*H_*4, 256, 0, stream>>>(t0, t1, t2);
        gemm_bf16_kernel<true,false,false,true><<<g512, 256, 0, stream>>>(
            t2, ow + (size_t)i*D_*D_, ob + i*D_, x, t0, M, D_, D_);
        ln_kernel<<<M, 64, 0, stream>>>(t0, ln1s + i*D_, ln1b + i*D_, x);
        gemm_bf16_kernel<true,true,false,false><<<g256, 256, 0, stream>>>(
            x, w1 + (size_t)i*D_*DFF_, b1 + i*DFF_, nullptr, t3, M, DFF_, D_);
        gemm_bf16_kernel<true,false,false,true><<<g512, 256, 0, stream>>>(
            t3, w2 + (size_t)i*DFF_*D_, b2 + i*D_, x, t2, M, D_, DFF_);
        ln_kernel<<<M, 64, 0, stream>>>(t2, ln2s + i*D_, ln2b + i*D_, x);
    }

    gemm_bf16_kernel<true,false,false,false><<<g512, 256, 0, stream>>>(
        x, ow1, ob1, nullptr, t0, M, FC1_, D_);
    gemm_bf16_kernel<false,true,true,false><<<g512, 256, 0, stream>>>(
        qe, ow1 + (size_t)D_*FC1_, nullptr, nullptr, t0, M, FC1_, D_);
    gemm_bf16_kernel<true,true,false,false><<<g256, 256, 0, stream>>>(
        t0, ow2, ob2, nullptr, t3, M, FC2_, FC1_);
    head_out_kernel<<<M, 64, 0, stream>>>(t3, ow3, ob3, out);
}